// Round 14
// baseline (457.121 us; speedup 1.0000x reference)
//
#include <hip/hip_runtime.h>

constexpr int F_IN   = 256;
constexpr int HID    = 128;
constexpr int NGRAPH = 512;
constexpr int NCOPY  = 8;

typedef short  short8 __attribute__((ext_vector_type(8)));
typedef float  f32x4  __attribute__((ext_vector_type(4)));

__device__ __forceinline__ unsigned short f2bf(float f) {
  union { float f; unsigned int u; } v = { f };
  unsigned int r = v.u + 0x7fffu + ((v.u >> 16) & 1u);
  return (unsigned short)(r >> 16);
}
__device__ __forceinline__ float bf2f(unsigned short h) {
  union { unsigned int u; float f; } v;
  v.u = ((unsigned int)h) << 16;
  return v.f;
}

__device__ __forceinline__ void gload16(const void* g, void* l) {
  __builtin_amdgcn_global_load_lds(
      (const __attribute__((address_space(1))) unsigned int*)g,
      (__attribute__((address_space(3))) unsigned int*)l, 16, 0, 0);
}
#define SB() __builtin_amdgcn_sched_barrier(0)

// ---------------- degree+count, privatized into 8 XCD-local copies ----------------
__global__ void deg_count_kernel(const int* __restrict__ col, const float* __restrict__ w,
                                 unsigned long long* __restrict__ packed8, int E, int N) {
  int e = blockIdx.x * blockDim.x + threadIdx.x;
  if (e < E) {
    const int j = blockIdx.x & (NCOPY - 1);       // ~XCD-local copy (perf only)
    const unsigned long long v =
        (1ull << 48) | (unsigned long long)((double)w[e] * 4294967296.0);
    atomicAdd(&packed8[(size_t)j * N + col[e]], v);
  }
}

// reduce 8 copies: dinv, total cnt, per-copy exclusive prefix (cps) + countdown (cdown)
__global__ void dinv_cnt_kernel(const unsigned long long* __restrict__ packed8,
                                float* __restrict__ dinv, int* __restrict__ cnt,
                                int* __restrict__ cps, int* __restrict__ cdown, int n) {
  int i = blockIdx.x * blockDim.x + threadIdx.x;
  if (i >= n) return;
  unsigned long long wsum = 0;
  int csum = 0;
#pragma unroll
  for (int j = 0; j < NCOPY; ++j) {
    const unsigned long long v = packed8[(size_t)j * n + i];
    const int cj = (int)(v >> 48);
    cps[(size_t)j * n + i] = csum;
    cdown[(size_t)j * n + i] = cj;
    csum += cj;
    wsum += v & 0xFFFFFFFFFFFFull;
  }
  cnt[i] = csum;
  const float d = (float)((double)wsum * (1.0 / 4294967296.0));
  dinv[i] = d > 0.f ? rsqrtf(d) : 0.f;
}

// ---------------- CSR build (by destination col) ----------------
__global__ void scan1_kernel(const int* __restrict__ cnt, int* __restrict__ psum, int N) {
  __shared__ int s[256];
  int i = blockIdx.x * 256 + threadIdx.x;
  s[threadIdx.x] = (i < N) ? cnt[i] : 0;
  __syncthreads();
  for (int o = 128; o > 0; o >>= 1) {
    if (threadIdx.x < o) s[threadIdx.x] += s[threadIdx.x + o];
    __syncthreads();
  }
  if (threadIdx.x == 0) psum[blockIdx.x] = s[0];
}

__global__ void scan2_kernel(int* __restrict__ psum, int nb) {
  __shared__ int s[512];
  __shared__ int carry_s;
  const int t = threadIdx.x;
  if (t == 0) carry_s = 0;
  __syncthreads();
  for (int base = 0; base < nb; base += 512) {
    const int i = base + t;
    const int v = (i < nb) ? psum[i] : 0;
    s[t] = v;
    __syncthreads();
    for (int o = 1; o < 512; o <<= 1) {
      const int u = (t >= o) ? s[t - o] : 0;
      __syncthreads();
      s[t] += u;
      __syncthreads();
    }
    const int carry = carry_s;
    if (i < nb) psum[i] = carry + s[t] - v;       // exclusive
    __syncthreads();
    if (t == 511) carry_s = carry + s[511];
    __syncthreads();
  }
}

__global__ void scan3_kernel(const int* __restrict__ cnt, const int* __restrict__ psum,
                             int* __restrict__ rowptr, int N, int E) {
  __shared__ int s[256];
  int i = blockIdx.x * 256 + threadIdx.x;
  int v = (i < N) ? cnt[i] : 0;
  s[threadIdx.x] = v;
  __syncthreads();
  for (int o = 1; o < 256; o <<= 1) {
    int t = (threadIdx.x >= o) ? s[threadIdx.x - o] : 0;
    __syncthreads();
    s[threadIdx.x] += t;
    __syncthreads();
  }
  if (i < N) rowptr[i] = psum[blockIdx.x] + s[threadIdx.x] - v;   // exclusive
  if (i == 0) rowptr[N] = E;
}

// fill: same grid geometry as deg_count -> same edge->copy mapping; private cursors
__global__ void fill_csr_kernel(const int* __restrict__ row, const int* __restrict__ col,
                                const float* __restrict__ ew, const float* __restrict__ dinv,
                                const int* __restrict__ rowptr,
                                const int* __restrict__ cps, int* __restrict__ cdown,
                                int2* __restrict__ cpay, int E, int N) {
  int e = blockIdx.x * blockDim.x + threadIdx.x;
  if (e >= E) return;
  const int j = blockIdx.x & (NCOPY - 1);
  const int r = row[e], c = col[e];
  const int idx = atomicSub(&cdown[(size_t)j * N + c], 1) - 1;
  const int p = rowptr[c] + cps[(size_t)j * N + c] + idx;
  int2 pay;
  pay.x = r;
  pay.y = __float_as_int(dinv[r] * ew[e] * dinv[c]);
  cpay[p] = pay;
}

// ---------------- weight prep: Bt[n][k] = [w_init | w_root], split hi/lo bf16 ----------------
__global__ void prep_w_kernel(const float* __restrict__ wi, const float* __restrict__ wr,
                              unsigned short* __restrict__ bth, unsigned short* __restrict__ btl,
                              int K) {
  int idx = blockIdx.x * 256 + threadIdx.x;
  if (idx >= 256 * K) return;
  const int n = idx / K, k = idx - n * K;
  const float f = (n < HID) ? wi[k * HID + n] : wr[k * HID + (n - HID)];
  const unsigned short h = f2bf(f);
  bth[idx] = h;
  btl[idx] = f2bf(f - bf2f(h));
}

// ======== conv0 GEMM (R7-best, measured 126 µs): fp32 A reg-stage+convert, direct B ========
template<int K>
__global__ __launch_bounds__(256)
void gemm_f32A(const float* __restrict__ A,
               const unsigned short* __restrict__ Bth, const unsigned short* __restrict__ Btl,
               unsigned short* __restrict__ Cinit, float* __restrict__ Croot, int M) {
  constexpr int NS = K / 32;
  __shared__ unsigned short HH[2][4][64][8];   // 8 KB
  __shared__ unsigned short LL[2][4][64][8];   // 8 KB
  const int lane = threadIdx.x & 63;
  const int wave = threadIdx.x >> 6;
  const int m0   = blockIdx.x * 64;
  const int cb   = wave * 64;
  const int lr   = lane & 15;
  const int lk   = (lane >> 4) * 8;

  const int srow = wave * 16 + (lane >> 2);
  int grow = m0 + srow; grow = grow < M ? grow : M - 1;
  const float* __restrict__ pA = &A[(size_t)grow * K + (lane & 3) * 8];
  const int dslot = (lane & 3) * 16 + (lane >> 2);

  f32x4 acc[4][4] = {};
  float4 g0, g1;

  auto stage_load = [&](int s) {
    g0 = *reinterpret_cast<const float4*>(pA + s * 32);
    g1 = *reinterpret_cast<const float4*>(pA + s * 32 + 4);
  };
  auto stage_write = [&](int s) {
    const int b = s & 1;
    const float f[8] = { g0.x, g0.y, g0.z, g0.w, g1.x, g1.y, g1.z, g1.w };
    unsigned int hw[4], lw[4];
#pragma unroll
    for (int j = 0; j < 4; ++j) {
      const unsigned short h0 = f2bf(f[2 * j]), h1 = f2bf(f[2 * j + 1]);
      hw[j] = (unsigned int)h0 | ((unsigned int)h1 << 16);
      const unsigned short l0 = f2bf(f[2 * j] - bf2f(h0));
      const unsigned short l1 = f2bf(f[2 * j + 1] - bf2f(h1));
      lw[j] = (unsigned int)l0 | ((unsigned int)l1 << 16);
    }
    *reinterpret_cast<uint4*>(&HH[b][wave][dslot][0]) = make_uint4(hw[0], hw[1], hw[2], hw[3]);
    *reinterpret_cast<uint4*>(&LL[b][wave][dslot][0]) = make_uint4(lw[0], lw[1], lw[2], lw[3]);
  };

  stage_load(0);
  stage_write(0);
  __syncthreads();

#pragma unroll
  for (int s = 0; s < NS; ++s) {
    if (s + 1 < NS) stage_load(s + 1);
    const int b = s & 1;
    short8 bh[4], bl[4];
#pragma unroll
    for (int ni = 0; ni < 4; ++ni) {
      const int colk = (cb + ni * 16 + lr) * K + s * 32 + lk;
      bh[ni] = *reinterpret_cast<const short8*>(&Bth[colk]);
      bl[ni] = *reinterpret_cast<const short8*>(&Btl[colk]);
    }
    short8 ah[4], al[4];
#pragma unroll
    for (int mi = 0; mi < 4; ++mi) {
      ah[mi] = *reinterpret_cast<const short8*>(&HH[b][mi][lane][0]);
      al[mi] = *reinterpret_cast<const short8*>(&LL[b][mi][lane][0]);
    }
#pragma unroll
    for (int ni = 0; ni < 4; ++ni) {
#pragma unroll
      for (int mi = 0; mi < 4; ++mi) {
        acc[mi][ni] = __builtin_amdgcn_mfma_f32_16x16x32_bf16(ah[mi], bh[ni], acc[mi][ni], 0, 0, 0);
        acc[mi][ni] = __builtin_amdgcn_mfma_f32_16x16x32_bf16(al[mi], bh[ni], acc[mi][ni], 0, 0, 0);
        acc[mi][ni] = __builtin_amdgcn_mfma_f32_16x16x32_bf16(ah[mi], bl[ni], acc[mi][ni], 0, 0, 0);
      }
    }
    if (s + 1 < NS) stage_write(s + 1);
    __syncthreads();
  }

#pragma unroll
  for (int mi = 0; mi < 4; ++mi) {
#pragma unroll
    for (int ni = 0; ni < 4; ++ni) {
      const int col = cb + ni * 16 + lr;
#pragma unroll
      for (int r = 0; r < 4; ++r) {
        const int row = m0 + mi * 16 + (lane >> 4) * 4 + r;
        if (row < M) {
          if (col < HID) Cinit[(size_t)row * HID + col] = f2bf(acc[mi][ni][r]);
          else           Croot[(size_t)row * HID + (col - HID)] = acc[mi][ni][r];
        }
      }
    }
  }
}

// ======== conv1 GEMM (R9): bf16 hi/lo A, pure global_load_lds staging, counted vmcnt ========
template<int K>
__global__ __launch_bounds__(256)
void gemm_bf16A(const unsigned short* __restrict__ Ah, const unsigned short* __restrict__ Al,
                const unsigned short* __restrict__ Bth, const unsigned short* __restrict__ Btl,
                unsigned short* __restrict__ Cinit, float* __restrict__ Croot, int M) {
  constexpr int NS = K / 32;
  __shared__ unsigned short HH[2][4][64][8];
  __shared__ unsigned short LL[2][4][64][8];
  __shared__ unsigned short BH[4][4][64][8];
  __shared__ unsigned short BL[4][4][64][8];
  const int lane = threadIdx.x & 63;
  const int wave = threadIdx.x >> 6;
  const int m0   = blockIdx.x * 64;
  const int cb   = wave * 64;
  const int lr   = lane & 15;
  const int lk   = (lane >> 4) * 8;

  int arow = m0 + wave * 16 + lr; arow = arow < M ? arow : M - 1;
  const size_t abase = (size_t)arow * K + lk;

  f32x4 acc[4][4] = {};

  auto issueA = [&](int s) {
    gload16(&Ah[abase + s * 32], &HH[s & 1][wave][0][0]);
    gload16(&Al[abase + s * 32], &LL[s & 1][wave][0][0]);
  };
  auto issueB = [&](int s) {
#pragma unroll
    for (int ni = 0; ni < 4; ++ni) {
      const size_t goff = (size_t)(cb + ni * 16 + lr) * K + s * 32 + lk;
      gload16(&Bth[goff], &BH[wave][ni][0][0]);
      gload16(&Btl[goff], &BL[wave][ni][0][0]);
    }
  };

  issueB(0);  SB();
  issueA(0);  SB();
  issueA(1);  SB();
  asm volatile("s_waitcnt vmcnt(2) lgkmcnt(0)" ::: "memory");
  SB();
  __builtin_amdgcn_s_barrier();
  SB();

#pragma unroll
  for (int s = 0; s < NS; ++s) {
    const int b = s & 1;
    short8 ah[4], al[4], bh[4], bl[4];
#pragma unroll
    for (int ni = 0; ni < 4; ++ni) {
      bh[ni] = *reinterpret_cast<const short8*>(&BH[wave][ni][lane][0]);
      bl[ni] = *reinterpret_cast<const short8*>(&BL[wave][ni][lane][0]);
    }
#pragma unroll
    for (int mi = 0; mi < 4; ++mi) {
      ah[mi] = *reinterpret_cast<const short8*>(&HH[b][mi][lane][0]);
      al[mi] = *reinterpret_cast<const short8*>(&LL[b][mi][lane][0]);
    }
    asm volatile("s_waitcnt lgkmcnt(0)" ::: "memory");
    SB();
    if (s + 1 < NS) issueB(s + 1);
    SB();
    if (s + 2 < NS) issueA(s + 2);
    SB();
#pragma unroll
    for (int ni = 0; ni < 4; ++ni) {
#pragma unroll
      for (int mi = 0; mi < 4; ++mi) {
        acc[mi][ni] = __builtin_amdgcn_mfma_f32_16x16x32_bf16(ah[mi], bh[ni], acc[mi][ni], 0, 0, 0);
        acc[mi][ni] = __builtin_amdgcn_mfma_f32_16x16x32_bf16(al[mi], bh[ni], acc[mi][ni], 0, 0, 0);
        acc[mi][ni] = __builtin_amdgcn_mfma_f32_16x16x32_bf16(ah[mi], bl[ni], acc[mi][ni], 0, 0, 0);
      }
    }
    if (s + 1 < NS) {
      if (s + 2 < NS) asm volatile("s_waitcnt vmcnt(2) lgkmcnt(0)" ::: "memory");
      else            asm volatile("s_waitcnt vmcnt(0) lgkmcnt(0)" ::: "memory");
      SB();
      __builtin_amdgcn_s_barrier();
      SB();
    }
  }

#pragma unroll
  for (int mi = 0; mi < 4; ++mi) {
#pragma unroll
    for (int ni = 0; ni < 4; ++ni) {
      const int col = cb + ni * 16 + lr;
#pragma unroll
      for (int r = 0; r < 4; ++r) {
        const int row = m0 + mi * 16 + (lane >> 4) * 4 + r;
        if (row < M) {
          if (col < HID) Cinit[(size_t)row * HID + col] = f2bf(acc[mi][ni][r]);
          else           Croot[(size_t)row * HID + (col - HID)] = acc[mi][ni][r];
        }
      }
    }
  }
}

// ---------------- gather conv0: 32 lanes/node, bf16 H, writes h as bf16 hi/lo pair ----------------
__global__ __launch_bounds__(256)
void gather1_kernel(const int* __restrict__ rowptr, const int2* __restrict__ cpay,
                    const unsigned short* __restrict__ H,
                    const float* __restrict__ root, const float* __restrict__ bias,
                    unsigned short* __restrict__ outh, unsigned short* __restrict__ outl,
                    int N) {
  const int l = threadIdx.x & 31;
  const int node = blockIdx.x * 8 + (threadIdx.x >> 5);
  if (node >= N) return;
  const int s = rowptr[node], t = rowptr[node + 1];
  float4 a = make_float4(0.f, 0.f, 0.f, 0.f);
  for (int p0 = s; p0 < t; p0 += 32) {
    const int np = min(32, t - p0);
    int2 pv = make_int2(0, 0);
    if (p0 + l < t) pv = cpay[p0 + l];
    const int   r = pv.x;
    const float w = __int_as_float(pv.y);
    int j = 0;
    for (; j + 4 <= np; j += 4) {
      const int   r0 = __shfl(r, j, 32),     r1 = __shfl(r, j + 1, 32);
      const int   r2 = __shfl(r, j + 2, 32), r3 = __shfl(r, j + 3, 32);
      const float w0 = __shfl(w, j, 32),     w1 = __shfl(w, j + 1, 32);
      const float w2 = __shfl(w, j + 2, 32), w3 = __shfl(w, j + 3, 32);
      const ushort4 h0 = *reinterpret_cast<const ushort4*>(&H[(size_t)r0 * HID + l * 4]);
      const ushort4 h1 = *reinterpret_cast<const ushort4*>(&H[(size_t)r1 * HID + l * 4]);
      const ushort4 h2 = *reinterpret_cast<const ushort4*>(&H[(size_t)r2 * HID + l * 4]);
      const ushort4 h3 = *reinterpret_cast<const ushort4*>(&H[(size_t)r3 * HID + l * 4]);
      a.x = fmaf(w0, bf2f(h0.x), a.x); a.y = fmaf(w0, bf2f(h0.y), a.y);
      a.z = fmaf(w0, bf2f(h0.z), a.z); a.w = fmaf(w0, bf2f(h0.w), a.w);
      a.x = fmaf(w1, bf2f(h1.x), a.x); a.y = fmaf(w1, bf2f(h1.y), a.y);
      a.z = fmaf(w1, bf2f(h1.z), a.z); a.w = fmaf(w1, bf2f(h1.w), a.w);
      a.x = fmaf(w2, bf2f(h2.x), a.x); a.y = fmaf(w2, bf2f(h2.y), a.y);
      a.z = fmaf(w2, bf2f(h2.z), a.z); a.w = fmaf(w2, bf2f(h2.w), a.w);
      a.x = fmaf(w3, bf2f(h3.x), a.x); a.y = fmaf(w3, bf2f(h3.y), a.y);
      a.z = fmaf(w3, bf2f(h3.z), a.z); a.w = fmaf(w3, bf2f(h3.w), a.w);
    }
    for (; j < np; ++j) {
      const int   rj = __shfl(r, j, 32);
      const float wj = __shfl(w, j, 32);
      const ushort4 hv = *reinterpret_cast<const ushort4*>(&H[(size_t)rj * HID + l * 4]);
      a.x = fmaf(wj, bf2f(hv.x), a.x); a.y = fmaf(wj, bf2f(hv.y), a.y);
      a.z = fmaf(wj, bf2f(hv.z), a.z); a.w = fmaf(wj, bf2f(hv.w), a.w);
    }
  }
  const float4 rv = *reinterpret_cast<const float4*>(&root[(size_t)node * HID + l * 4]);
  const float4 bv = *reinterpret_cast<const float4*>(&bias[l * 4]);
  float o[4];
  o[0] = fmaxf(a.x + rv.x + bv.x, 0.f);
  o[1] = fmaxf(a.y + rv.y + bv.y, 0.f);
  o[2] = fmaxf(a.z + rv.z + bv.z, 0.f);
  o[3] = fmaxf(a.w + rv.w + bv.w, 0.f);
  ushort4 oh, ol;
  unsigned short* ph = &oh.x; unsigned short* pl = &ol.x;
#pragma unroll
  for (int j = 0; j < 4; ++j) {
    const unsigned short h = f2bf(o[j]);
    ph[j] = h;
    pl[j] = f2bf(o[j] - bf2f(h));
  }
  *reinterpret_cast<ushort4*>(&outh[(size_t)node * HID + l * 4]) = oh;
  *reinterpret_cast<ushort4*>(&outl[(size_t)node * HID + l * 4]) = ol;
}

// ---------------- FUSED gather conv1 + mean-pool: 16 nodes/block, 2 batches of 8 ----------------
__global__ __launch_bounds__(256)
void gather_pool_kernel(const int* __restrict__ rowptr, const int2* __restrict__ cpay,
                        const unsigned short* __restrict__ H,
                        const float* __restrict__ root, const float* __restrict__ bias,
                        const int* __restrict__ batch,
                        float* __restrict__ gsum, float* __restrict__ gcnt, int N) {
  __shared__ float nx[8][HID];
  __shared__ int gid[8];
  const int l = threadIdx.x & 31;
  const int g = threadIdx.x >> 5;
  const int f = threadIdx.x;

  float acc = 0.f, crun = 0.f; int cur = -1;

  for (int b = 0; b < 2; ++b) {
    const int node = blockIdx.x * 16 + b * 8 + g;
    const bool valid = node < N;
    float o[4] = { 0.f, 0.f, 0.f, 0.f };
    if (valid) {
      const int s = rowptr[node], t = rowptr[node + 1];
      float4 a = make_float4(0.f, 0.f, 0.f, 0.f);
      for (int p0 = s; p0 < t; p0 += 32) {
        const int np = min(32, t - p0);
        int2 pv = make_int2(0, 0);
        if (p0 + l < t) pv = cpay[p0 + l];
        const int   r = pv.x;
        const float w = __int_as_float(pv.y);
        int j = 0;
        for (; j + 4 <= np; j += 4) {
          const int   r0 = __shfl(r, j, 32),     r1 = __shfl(r, j + 1, 32);
          const int   r2 = __shfl(r, j + 2, 32), r3 = __shfl(r, j + 3, 32);
          const float w0 = __shfl(w, j, 32),     w1 = __shfl(w, j + 1, 32);
          const float w2 = __shfl(w, j + 2, 32), w3 = __shfl(w, j + 3, 32);
          const ushort4 h0 = *reinterpret_cast<const ushort4*>(&H[(size_t)r0 * HID + l * 4]);
          const ushort4 h1 = *reinterpret_cast<const ushort4*>(&H[(size_t)r1 * HID + l * 4]);
          const ushort4 h2 = *reinterpret_cast<const ushort4*>(&H[(size_t)r2 * HID + l * 4]);
          const ushort4 h3 = *reinterpret_cast<const ushort4*>(&H[(size_t)r3 * HID + l * 4]);
          a.x = fmaf(w0, bf2f(h0.x), a.x); a.y = fmaf(w0, bf2f(h0.y), a.y);
          a.z = fmaf(w0, bf2f(h0.z), a.z); a.w = fmaf(w0, bf2f(h0.w), a.w);
          a.x = fmaf(w1, bf2f(h1.x), a.x); a.y = fmaf(w1, bf2f(h1.y), a.y);
          a.z = fmaf(w1, bf2f(h1.z), a.z); a.w = fmaf(w1, bf2f(h1.w), a.w);
          a.x = fmaf(w2, bf2f(h2.x), a.x); a.y = fmaf(w2, bf2f(h2.y), a.y);
          a.z = fmaf(w2, bf2f(h2.z), a.z); a.w = fmaf(w2, bf2f(h2.w), a.w);
          a.x = fmaf(w3, bf2f(h3.x), a.x); a.y = fmaf(w3, bf2f(h3.y), a.y);
          a.z = fmaf(w3, bf2f(h3.z), a.z); a.w = fmaf(w3, bf2f(h3.w), a.w);
        }
        for (; j < np; ++j) {
          const int   rj = __shfl(r, j, 32);
          const float wj = __shfl(w, j, 32);
          const ushort4 hv = *reinterpret_cast<const ushort4*>(&H[(size_t)rj * HID + l * 4]);
          a.x = fmaf(wj, bf2f(hv.x), a.x); a.y = fmaf(wj, bf2f(hv.y), a.y);
          a.z = fmaf(wj, bf2f(hv.z), a.z); a.w = fmaf(wj, bf2f(hv.w), a.w);
        }
      }
      const float4 rv = *reinterpret_cast<const float4*>(&root[(size_t)node * HID + l * 4]);
      const float4 bv = *reinterpret_cast<const float4*>(&bias[l * 4]);
      o[0] = fmaxf(a.x + rv.x + bv.x, 0.f);
      o[1] = fmaxf(a.y + rv.y + bv.y, 0.f);
      o[2] = fmaxf(a.z + rv.z + bv.z, 0.f);
      o[3] = fmaxf(a.w + rv.w + bv.w, 0.f);
    }
    if (l == 0) gid[g] = valid ? batch[node] : -1;
    *reinterpret_cast<float4*>(&nx[g][l * 4]) = make_float4(o[0], o[1], o[2], o[3]);
    __syncthreads();
    if (f < HID) {
      for (int i = 0; i < 8; ++i) {
        const int gi = gid[i];
        if (gi < 0) continue;
        if (gi != cur) {
          if (cur >= 0) {
            atomicAdd(&gsum[cur * HID + f], acc);
            if (f == 0) atomicAdd(&gcnt[cur], crun);
          }
          acc = 0.f; crun = 0.f; cur = gi;
        }
        acc += nx[i][f]; crun += 1.f;
      }
    }
    __syncthreads();
  }
  if (f < HID && cur >= 0) {
    atomicAdd(&gsum[cur * HID + f], acc);
    if (f == 0) atomicAdd(&gcnt[cur], crun);
  }
}

// ---------------- graph MLP ----------------
__global__ __launch_bounds__(256)
void mlp_kernel(const float* __restrict__ gsum, const float* __restrict__ gcnt,
                const float* __restrict__ w1, const float* __restrict__ b1,
                const float* __restrict__ w2, const float* __restrict__ b2,
                float* __restrict__ out) {
  const int g = blockIdx.x;
  const int t = threadIdx.x;
  __shared__ float gx[HID];
  __shared__ float red[8];
  const float cnt = fmaxf(gcnt[g], 1.f);
  if (t < HID) gx[t] = gsum[g * HID + t] / cnt;
  __syncthreads();
  float a = b1[t];
  for (int k = 0; k < HID; ++k) a = fmaf(gx[k], w1[k * 256 + t], a);
  const float h = fmaxf(a, 0.f);
  float p0 = h * w2[t * 2 + 0];
  float p1 = h * w2[t * 2 + 1];
  for (int o = 32; o > 0; o >>= 1) { p0 += __shfl_down(p0, o, 64); p1 += __shfl_down(p1, o, 64); }
  const int lane = t & 63, wv = t >> 6;
  if (lane == 0) { red[wv * 2] = p0; red[wv * 2 + 1] = p1; }
  __syncthreads();
  if (t == 0) out[g * 2 + 0] = red[0] + red[2] + red[4] + red[6] + b2[0];
  if (t == 1) out[g * 2 + 1] = red[1] + red[3] + red[5] + red[7] + b2[1];
}

extern "C" void kernel_launch(void* const* d_in, const int* in_sizes, int n_in,
                              void* d_out, int out_size, void* d_ws, size_t ws_size,
                              hipStream_t stream) {
  const float* x       = (const float*)d_in[0];
  const int*   ei      = (const int*)d_in[1];
  const float* ea      = (const float*)d_in[2];
  const int*   batch   = (const int*)d_in[3];
  const float* w_init0 = (const float*)d_in[4];
  const float* w_root0 = (const float*)d_in[5];
  const float* b0      = (const float*)d_in[6];
  const float* w_init1 = (const float*)d_in[7];
  const float* w_root1 = (const float*)d_in[8];
  const float* b1      = (const float*)d_in[9];
  const float* mw1     = (const float*)d_in[10];
  const float* mb1     = (const float*)d_in[11];
  const float* mw2     = (const float*)d_in[12];
  const float* mb2     = (const float*)d_in[13];
  float* out = (float*)d_out;

  const int E = in_sizes[2];
  const int N = in_sizes[3];
  const int* row = ei;
  const int* col = ei + E;
  const int nb = (N + 255) / 256;

  char* ws = (char*)d_ws;
  size_t off = 0;
  auto alloc = [&](size_t bytes) -> void* {
    size_t cur = off;
    off = (cur + bytes + 255) & ~(size_t)255;
    return (void*)(ws + cur);
  };
  unsigned long long* packed8 = (unsigned long long*)alloc((size_t)NCOPY * N * 8);
  float* dinv   = (float*)alloc((size_t)N * 4);
  int*   cnt    = (int*)alloc((size_t)N * 4);
  int*   cps    = (int*)alloc((size_t)NCOPY * N * 4);
  int*   cdown  = (int*)alloc((size_t)NCOPY * N * 4);
  int*   psum   = (int*)alloc((size_t)nb * 4);
  int*   rowptr = (int*)alloc((size_t)(N + 1) * 4);
  int2*  cpay   = (int2*)alloc((size_t)E * 8);
  unsigned short* B1  = (unsigned short*)alloc((size_t)N * HID * 2);  // H (bf16 gather operand)
  unsigned short* B2h = (unsigned short*)alloc((size_t)N * HID * 2);  // h hi
  unsigned short* B2l = (unsigned short*)alloc((size_t)N * HID * 2);  // h lo
  float* B3     = (float*)alloc((size_t)N * HID * 4);  // conv0 root -> conv1 root
  unsigned short* w0h = (unsigned short*)alloc((size_t)256 * F_IN * 2);
  unsigned short* w0l = (unsigned short*)alloc((size_t)256 * F_IN * 2);
  unsigned short* w1h = (unsigned short*)alloc((size_t)256 * HID * 2);
  unsigned short* w1l = (unsigned short*)alloc((size_t)256 * HID * 2);
  float* gsum   = (float*)alloc((size_t)NGRAPH * HID * 4);
  float* gcnt   = (float*)alloc((size_t)NGRAPH * 4);
  (void)ws_size; (void)n_in; (void)out_size;

  // ---- gcn_norm + CSR build (privatized atomics) + weight prep ----
  hipMemsetAsync(packed8, 0, (size_t)NCOPY * N * 8, stream);
  deg_count_kernel<<<(E + 255) / 256, 256, 0, stream>>>(col, ea, packed8, E, N);
  dinv_cnt_kernel<<<(N + 255) / 256, 256, 0, stream>>>(packed8, dinv, cnt, cps, cdown, N);
  scan1_kernel<<<nb, 256, 0, stream>>>(cnt, psum, N);
  scan2_kernel<<<1, 512, 0, stream>>>(psum, nb);
  scan3_kernel<<<nb, 256, 0, stream>>>(cnt, psum, rowptr, N, E);
  fill_csr_kernel<<<(E + 255) / 256, 256, 0, stream>>>(row, col, ea, dinv, rowptr,
                                                       cps, cdown, cpay, E, N);
  prep_w_kernel<<<(256 * F_IN + 255) / 256, 256, 0, stream>>>(w_init0, w_root0, w0h, w0l, F_IN);
  prep_w_kernel<<<(256 * HID + 255) / 256, 256, 0, stream>>>(w_init1, w_root1, w1h, w1l, HID);

  const int gb = (N + 63) / 64;

  // ---- conv0: B1 = bf16(x@wi0), B3 = x@wr0; gather -> (B2h,B2l) = split(relu(...)) ----
  gemm_f32A<F_IN><<<gb, 256, 0, stream>>>(x, w0h, w0l, B1, B3, N);
  gather1_kernel<<<(N + 7) / 8, 256, 0, stream>>>(rowptr, cpay, B1, B3, b0, B2h, B2l, N);

  // ---- conv1: B1 = bf16(h@wi1), B3 = h@wr1; fused gather+pool (no node_x writeback) ----
  gemm_bf16A<HID><<<gb, 256, 0, stream>>>(B2h, B2l, w1h, w1l, B1, B3, N);
  hipMemsetAsync(gsum, 0, (size_t)NGRAPH * HID * 4, stream);
  hipMemsetAsync(gcnt, 0, (size_t)NGRAPH * 4, stream);
  gather_pool_kernel<<<(N + 15) / 16, 256, 0, stream>>>(rowptr, cpay, B1, B3, b1, batch,
                                                        gsum, gcnt, N);

  // ---- MLP ----
  mlp_kernel<<<NGRAPH, 256, 0, stream>>>(gsum, gcnt, mw1, mb1, mw2, mb2, out);
}

// Round 15
// 442.734 us; speedup vs baseline: 1.0325x; 1.0325x over previous
//
#include <hip/hip_runtime.h>

constexpr int F_IN   = 256;
constexpr int HID    = 128;
constexpr int NGRAPH = 512;

typedef short  short8 __attribute__((ext_vector_type(8)));
typedef float  f32x4  __attribute__((ext_vector_type(4)));

__device__ __forceinline__ unsigned short f2bf(float f) {
  union { float f; unsigned int u; } v = { f };
  unsigned int r = v.u + 0x7fffu + ((v.u >> 16) & 1u);
  return (unsigned short)(r >> 16);
}
__device__ __forceinline__ float bf2f(unsigned short h) {
  union { unsigned int u; float f; } v;
  v.u = ((unsigned int)h) << 16;
  return v.f;
}

__device__ __forceinline__ void gload16(const void* g, void* l) {
  __builtin_amdgcn_global_load_lds(
      (const __attribute__((address_space(1))) unsigned int*)g,
      (__attribute__((address_space(3))) unsigned int*)l, 16, 0, 0);
}
#define SB() __builtin_amdgcn_sched_barrier(0)

// ---------------- degree + count in ONE 64-bit atomic per edge ----------------
__global__ void deg_count_kernel(const int* __restrict__ col, const float* __restrict__ w,
                                 unsigned long long* __restrict__ packed, int E) {
  int e = blockIdx.x * blockDim.x + threadIdx.x;
  if (e < E) {
    const unsigned long long v =
        (1ull << 48) | (unsigned long long)((double)w[e] * 4294967296.0);
    atomicAdd(&packed[col[e]], v);
  }
}

__global__ void dinv_cnt_kernel(const unsigned long long* __restrict__ packed,
                                float* __restrict__ dinv, int* __restrict__ cnt, int n) {
  int i = blockIdx.x * blockDim.x + threadIdx.x;
  if (i >= n) return;
  const unsigned long long v = packed[i];
  const int c = (int)(v >> 48);
  const float d = (float)((double)(v & 0xFFFFFFFFFFFFull) * (1.0 / 4294967296.0));
  cnt[i] = c;
  dinv[i] = d > 0.f ? rsqrtf(d) : 0.f;
}

// ---------------- CSR build (by destination col) ----------------
__global__ void scan1_kernel(const int* __restrict__ cnt, int* __restrict__ psum, int N) {
  __shared__ int s[256];
  int i = blockIdx.x * 256 + threadIdx.x;
  s[threadIdx.x] = (i < N) ? cnt[i] : 0;
  __syncthreads();
  for (int o = 128; o > 0; o >>= 1) {
    if (threadIdx.x < o) s[threadIdx.x] += s[threadIdx.x + o];
    __syncthreads();
  }
  if (threadIdx.x == 0) psum[blockIdx.x] = s[0];
}

__global__ void scan2_kernel(int* __restrict__ psum, int nb) {
  __shared__ int s[512];
  __shared__ int carry_s;
  const int t = threadIdx.x;
  if (t == 0) carry_s = 0;
  __syncthreads();
  for (int base = 0; base < nb; base += 512) {
    const int i = base + t;
    const int v = (i < nb) ? psum[i] : 0;
    s[t] = v;
    __syncthreads();
    for (int o = 1; o < 512; o <<= 1) {
      const int u = (t >= o) ? s[t - o] : 0;
      __syncthreads();
      s[t] += u;
      __syncthreads();
    }
    const int carry = carry_s;
    if (i < nb) psum[i] = carry + s[t] - v;       // exclusive
    __syncthreads();
    if (t == 511) carry_s = carry + s[511];
    __syncthreads();
  }
}

__global__ void scan3_kernel(const int* __restrict__ cnt, const int* __restrict__ psum,
                             int* __restrict__ rowptr, int N, int E) {
  __shared__ int s[256];
  int i = blockIdx.x * 256 + threadIdx.x;
  int v = (i < N) ? cnt[i] : 0;
  s[threadIdx.x] = v;
  __syncthreads();
  for (int o = 1; o < 256; o <<= 1) {
    int t = (threadIdx.x >= o) ? s[threadIdx.x - o] : 0;
    __syncthreads();
    s[threadIdx.x] += t;
    __syncthreads();
  }
  if (i < N) rowptr[i] = psum[blockIdx.x] + s[threadIdx.x] - v;   // exclusive
  if (i == 0) rowptr[N] = E;
}

// fill: payload (src row, full norm = dinv[r]*w*dinv[c]); cnt reused as cursor
__global__ void fill_csr_kernel(const int* __restrict__ row, const int* __restrict__ col,
                                const float* __restrict__ ew, const float* __restrict__ dinv,
                                const int* __restrict__ rowptr, int* __restrict__ cnt,
                                int2* __restrict__ cpay, int E) {
  int e = blockIdx.x * blockDim.x + threadIdx.x;
  if (e >= E) return;
  const int r = row[e], c = col[e];
  const int idx = atomicSub(&cnt[c], 1) - 1;
  const int p = rowptr[c] + idx;
  int2 pay;
  pay.x = r;
  pay.y = __float_as_int(dinv[r] * ew[e] * dinv[c]);
  cpay[p] = pay;
}

// ---------------- weight prep: Bt[n][k] = [w_init | w_root], split hi/lo bf16 ----------------
__global__ void prep_w_kernel(const float* __restrict__ wi, const float* __restrict__ wr,
                              unsigned short* __restrict__ bth, unsigned short* __restrict__ btl,
                              int K) {
  int idx = blockIdx.x * 256 + threadIdx.x;
  if (idx >= 256 * K) return;
  const int n = idx / K, k = idx - n * K;
  const float f = (n < HID) ? wi[k * HID + n] : wr[k * HID + (n - HID)];
  const unsigned short h = f2bf(f);
  bth[idx] = h;
  btl[idx] = f2bf(f - bf2f(h));
}

// ======== conv0 GEMM (R7-best, measured 126 µs): fp32 A reg-stage+convert, direct B ========
// Cinit (bf16) = A@Winit; Croot (fp32) = A@Wroot.  C = Ah*Bh + Al*Bh + Ah*Bl.
template<int K>
__global__ __launch_bounds__(256)
void gemm_f32A(const float* __restrict__ A,
               const unsigned short* __restrict__ Bth, const unsigned short* __restrict__ Btl,
               unsigned short* __restrict__ Cinit, float* __restrict__ Croot, int M) {
  constexpr int NS = K / 32;
  __shared__ unsigned short HH[2][4][64][8];   // 8 KB
  __shared__ unsigned short LL[2][4][64][8];   // 8 KB
  const int lane = threadIdx.x & 63;
  const int wave = threadIdx.x >> 6;
  const int m0   = blockIdx.x * 64;
  const int cb   = wave * 64;
  const int lr   = lane & 15;
  const int lk   = (lane >> 4) * 8;

  const int srow = wave * 16 + (lane >> 2);
  int grow = m0 + srow; grow = grow < M ? grow : M - 1;
  const float* __restrict__ pA = &A[(size_t)grow * K + (lane & 3) * 8];
  const int dslot = (lane & 3) * 16 + (lane >> 2);

  f32x4 acc[4][4] = {};
  float4 g0, g1;

  auto stage_load = [&](int s) {
    g0 = *reinterpret_cast<const float4*>(pA + s * 32);
    g1 = *reinterpret_cast<const float4*>(pA + s * 32 + 4);
  };
  auto stage_write = [&](int s) {
    const int b = s & 1;
    const float f[8] = { g0.x, g0.y, g0.z, g0.w, g1.x, g1.y, g1.z, g1.w };
    unsigned int hw[4], lw[4];
#pragma unroll
    for (int j = 0; j < 4; ++j) {
      const unsigned short h0 = f2bf(f[2 * j]), h1 = f2bf(f[2 * j + 1]);
      hw[j] = (unsigned int)h0 | ((unsigned int)h1 << 16);
      const unsigned short l0 = f2bf(f[2 * j] - bf2f(h0));
      const unsigned short l1 = f2bf(f[2 * j + 1] - bf2f(h1));
      lw[j] = (unsigned int)l0 | ((unsigned int)l1 << 16);
    }
    *reinterpret_cast<uint4*>(&HH[b][wave][dslot][0]) = make_uint4(hw[0], hw[1], hw[2], hw[3]);
    *reinterpret_cast<uint4*>(&LL[b][wave][dslot][0]) = make_uint4(lw[0], lw[1], lw[2], lw[3]);
  };

  stage_load(0);
  stage_write(0);
  __syncthreads();

#pragma unroll
  for (int s = 0; s < NS; ++s) {
    if (s + 1 < NS) stage_load(s + 1);
    const int b = s & 1;
    short8 bh[4], bl[4];
#pragma unroll
    for (int ni = 0; ni < 4; ++ni) {
      const int colk = (cb + ni * 16 + lr) * K + s * 32 + lk;
      bh[ni] = *reinterpret_cast<const short8*>(&Bth[colk]);
      bl[ni] = *reinterpret_cast<const short8*>(&Btl[colk]);
    }
    short8 ah[4], al[4];
#pragma unroll
    for (int mi = 0; mi < 4; ++mi) {
      ah[mi] = *reinterpret_cast<const short8*>(&HH[b][mi][lane][0]);
      al[mi] = *reinterpret_cast<const short8*>(&LL[b][mi][lane][0]);
    }
#pragma unroll
    for (int ni = 0; ni < 4; ++ni) {
#pragma unroll
      for (int mi = 0; mi < 4; ++mi) {
        acc[mi][ni] = __builtin_amdgcn_mfma_f32_16x16x32_bf16(ah[mi], bh[ni], acc[mi][ni], 0, 0, 0);
        acc[mi][ni] = __builtin_amdgcn_mfma_f32_16x16x32_bf16(al[mi], bh[ni], acc[mi][ni], 0, 0, 0);
        acc[mi][ni] = __builtin_amdgcn_mfma_f32_16x16x32_bf16(ah[mi], bl[ni], acc[mi][ni], 0, 0, 0);
      }
    }
    if (s + 1 < NS) stage_write(s + 1);
    __syncthreads();
  }

  // epilogue: C/D layout col = lane&15, row = (lane>>4)*4 + r
#pragma unroll
  for (int mi = 0; mi < 4; ++mi) {
#pragma unroll
    for (int ni = 0; ni < 4; ++ni) {
      const int col = cb + ni * 16 + lr;
#pragma unroll
      for (int r = 0; r < 4; ++r) {
        const int row = m0 + mi * 16 + (lane >> 4) * 4 + r;
        if (row < M) {
          if (col < HID) Cinit[(size_t)row * HID + col] = f2bf(acc[mi][ni][r]);
          else           Croot[(size_t)row * HID + (col - HID)] = acc[mi][ni][r];
        }
      }
    }
  }
}

// ======== conv1 GEMM (R9): bf16 hi/lo A, pure global_load_lds staging, counted vmcnt ========
template<int K>
__global__ __launch_bounds__(256)
void gemm_bf16A(const unsigned short* __restrict__ Ah, const unsigned short* __restrict__ Al,
                const unsigned short* __restrict__ Bth, const unsigned short* __restrict__ Btl,
                unsigned short* __restrict__ Cinit, float* __restrict__ Croot, int M) {
  constexpr int NS = K / 32;
  __shared__ unsigned short HH[2][4][64][8];
  __shared__ unsigned short LL[2][4][64][8];
  __shared__ unsigned short BH[4][4][64][8];
  __shared__ unsigned short BL[4][4][64][8];
  const int lane = threadIdx.x & 63;
  const int wave = threadIdx.x >> 6;
  const int m0   = blockIdx.x * 64;
  const int cb   = wave * 64;
  const int lr   = lane & 15;
  const int lk   = (lane >> 4) * 8;

  int arow = m0 + wave * 16 + lr; arow = arow < M ? arow : M - 1;
  const size_t abase = (size_t)arow * K + lk;

  f32x4 acc[4][4] = {};

  auto issueA = [&](int s) {
    gload16(&Ah[abase + s * 32], &HH[s & 1][wave][0][0]);
    gload16(&Al[abase + s * 32], &LL[s & 1][wave][0][0]);
  };
  auto issueB = [&](int s) {
#pragma unroll
    for (int ni = 0; ni < 4; ++ni) {
      const size_t goff = (size_t)(cb + ni * 16 + lr) * K + s * 32 + lk;
      gload16(&Bth[goff], &BH[wave][ni][0][0]);
      gload16(&Btl[goff], &BL[wave][ni][0][0]);
    }
  };

  issueB(0);  SB();
  issueA(0);  SB();
  issueA(1);  SB();
  asm volatile("s_waitcnt vmcnt(2) lgkmcnt(0)" ::: "memory");
  SB();
  __builtin_amdgcn_s_barrier();
  SB();

#pragma unroll
  for (int s = 0; s < NS; ++s) {
    const int b = s & 1;
    short8 ah[4], al[4], bh[4], bl[4];
#pragma unroll
    for (int ni = 0; ni < 4; ++ni) {
      bh[ni] = *reinterpret_cast<const short8*>(&BH[wave][ni][lane][0]);
      bl[ni] = *reinterpret_cast<const short8*>(&BL[wave][ni][lane][0]);
    }
#pragma unroll
    for (int mi = 0; mi < 4; ++mi) {
      ah[mi] = *reinterpret_cast<const short8*>(&HH[b][mi][lane][0]);
      al[mi] = *reinterpret_cast<const short8*>(&LL[b][mi][lane][0]);
    }
    asm volatile("s_waitcnt lgkmcnt(0)" ::: "memory");
    SB();
    if (s + 1 < NS) issueB(s + 1);
    SB();
    if (s + 2 < NS) issueA(s + 2);
    SB();
#pragma unroll
    for (int ni = 0; ni < 4; ++ni) {
#pragma unroll
      for (int mi = 0; mi < 4; ++mi) {
        acc[mi][ni] = __builtin_amdgcn_mfma_f32_16x16x32_bf16(ah[mi], bh[ni], acc[mi][ni], 0, 0, 0);
        acc[mi][ni] = __builtin_amdgcn_mfma_f32_16x16x32_bf16(al[mi], bh[ni], acc[mi][ni], 0, 0, 0);
        acc[mi][ni] = __builtin_amdgcn_mfma_f32_16x16x32_bf16(ah[mi], bl[ni], acc[mi][ni], 0, 0, 0);
      }
    }
    if (s + 1 < NS) {
      if (s + 2 < NS) asm volatile("s_waitcnt vmcnt(2) lgkmcnt(0)" ::: "memory");
      else            asm volatile("s_waitcnt vmcnt(0) lgkmcnt(0)" ::: "memory");
      SB();
      __builtin_amdgcn_s_barrier();
      SB();
    }
  }

#pragma unroll
  for (int mi = 0; mi < 4; ++mi) {
#pragma unroll
    for (int ni = 0; ni < 4; ++ni) {
      const int col = cb + ni * 16 + lr;
#pragma unroll
      for (int r = 0; r < 4; ++r) {
        const int row = m0 + mi * 16 + (lane >> 4) * 4 + r;
        if (row < M) {
          if (col < HID) Cinit[(size_t)row * HID + col] = f2bf(acc[mi][ni][r]);
          else           Croot[(size_t)row * HID + (col - HID)] = acc[mi][ni][r];
        }
      }
    }
  }
}

// ---------------- gather conv0: 32 lanes/node, bf16 H, writes h as bf16 hi/lo pair ----------------
__global__ __launch_bounds__(256)
void gather1_kernel(const int* __restrict__ rowptr, const int2* __restrict__ cpay,
                    const unsigned short* __restrict__ H,
                    const float* __restrict__ root, const float* __restrict__ bias,
                    unsigned short* __restrict__ outh, unsigned short* __restrict__ outl,
                    int N) {
  const int l = threadIdx.x & 31;
  const int node = blockIdx.x * 8 + (threadIdx.x >> 5);
  if (node >= N) return;
  const int s = rowptr[node], t = rowptr[node + 1];
  float4 a = make_float4(0.f, 0.f, 0.f, 0.f);
  for (int p0 = s; p0 < t; p0 += 32) {
    const int np = min(32, t - p0);
    int2 pv = make_int2(0, 0);
    if (p0 + l < t) pv = cpay[p0 + l];
    const int   r = pv.x;
    const float w = __int_as_float(pv.y);
    int j = 0;
    for (; j + 4 <= np; j += 4) {
      const int   r0 = __shfl(r, j, 32),     r1 = __shfl(r, j + 1, 32);
      const int   r2 = __shfl(r, j + 2, 32), r3 = __shfl(r, j + 3, 32);
      const float w0 = __shfl(w, j, 32),     w1 = __shfl(w, j + 1, 32);
      const float w2 = __shfl(w, j + 2, 32), w3 = __shfl(w, j + 3, 32);
      const ushort4 h0 = *reinterpret_cast<const ushort4*>(&H[(size_t)r0 * HID + l * 4]);
      const ushort4 h1 = *reinterpret_cast<const ushort4*>(&H[(size_t)r1 * HID + l * 4]);
      const ushort4 h2 = *reinterpret_cast<const ushort4*>(&H[(size_t)r2 * HID + l * 4]);
      const ushort4 h3 = *reinterpret_cast<const ushort4*>(&H[(size_t)r3 * HID + l * 4]);
      a.x = fmaf(w0, bf2f(h0.x), a.x); a.y = fmaf(w0, bf2f(h0.y), a.y);
      a.z = fmaf(w0, bf2f(h0.z), a.z); a.w = fmaf(w0, bf2f(h0.w), a.w);
      a.x = fmaf(w1, bf2f(h1.x), a.x); a.y = fmaf(w1, bf2f(h1.y), a.y);
      a.z = fmaf(w1, bf2f(h1.z), a.z); a.w = fmaf(w1, bf2f(h1.w), a.w);
      a.x = fmaf(w2, bf2f(h2.x), a.x); a.y = fmaf(w2, bf2f(h2.y), a.y);
      a.z = fmaf(w2, bf2f(h2.z), a.z); a.w = fmaf(w2, bf2f(h2.w), a.w);
      a.x = fmaf(w3, bf2f(h3.x), a.x); a.y = fmaf(w3, bf2f(h3.y), a.y);
      a.z = fmaf(w3, bf2f(h3.z), a.z); a.w = fmaf(w3, bf2f(h3.w), a.w);
    }
    for (; j < np; ++j) {
      const int   rj = __shfl(r, j, 32);
      const float wj = __shfl(w, j, 32);
      const ushort4 hv = *reinterpret_cast<const ushort4*>(&H[(size_t)rj * HID + l * 4]);
      a.x = fmaf(wj, bf2f(hv.x), a.x); a.y = fmaf(wj, bf2f(hv.y), a.y);
      a.z = fmaf(wj, bf2f(hv.z), a.z); a.w = fmaf(wj, bf2f(hv.w), a.w);
    }
  }
  const float4 rv = *reinterpret_cast<const float4*>(&root[(size_t)node * HID + l * 4]);
  const float4 bv = *reinterpret_cast<const float4*>(&bias[l * 4]);
  float o[4];
  o[0] = fmaxf(a.x + rv.x + bv.x, 0.f);
  o[1] = fmaxf(a.y + rv.y + bv.y, 0.f);
  o[2] = fmaxf(a.z + rv.z + bv.z, 0.f);
  o[3] = fmaxf(a.w + rv.w + bv.w, 0.f);
  ushort4 oh, ol;
  unsigned short* ph = &oh.x; unsigned short* pl = &ol.x;
#pragma unroll
  for (int j = 0; j < 4; ++j) {
    const unsigned short h = f2bf(o[j]);
    ph[j] = h;
    pl[j] = f2bf(o[j] - bf2f(h));
  }
  *reinterpret_cast<ushort4*>(&outh[(size_t)node * HID + l * 4]) = oh;
  *reinterpret_cast<ushort4*>(&outl[(size_t)node * HID + l * 4]) = ol;
}

// ---------------- FUSED gather conv1 + mean-pool: 16 nodes/block, 2 batches of 8 ----------------
// node_x never hits HBM; per-block LDS staging + run-accumulated atomic flush (batch sorted).
__global__ __launch_bounds__(256)
void gather_pool_kernel(const int* __restrict__ rowptr, const int2* __restrict__ cpay,
                        const unsigned short* __restrict__ H,
                        const float* __restrict__ root, const float* __restrict__ bias,
                        const int* __restrict__ batch,
                        float* __restrict__ gsum, float* __restrict__ gcnt, int N) {
  __shared__ float nx[8][HID];
  __shared__ int gid[8];
  const int l = threadIdx.x & 31;
  const int g = threadIdx.x >> 5;
  const int f = threadIdx.x;

  float acc = 0.f, crun = 0.f; int cur = -1;   // run accumulator, carried across batches

  for (int b = 0; b < 2; ++b) {
    const int node = blockIdx.x * 16 + b * 8 + g;
    const bool valid = node < N;
    float o[4] = { 0.f, 0.f, 0.f, 0.f };
    if (valid) {
      const int s = rowptr[node], t = rowptr[node + 1];
      float4 a = make_float4(0.f, 0.f, 0.f, 0.f);
      for (int p0 = s; p0 < t; p0 += 32) {
        const int np = min(32, t - p0);
        int2 pv = make_int2(0, 0);
        if (p0 + l < t) pv = cpay[p0 + l];
        const int   r = pv.x;
        const float w = __int_as_float(pv.y);
        int j = 0;
        for (; j + 4 <= np; j += 4) {
          const int   r0 = __shfl(r, j, 32),     r1 = __shfl(r, j + 1, 32);
          const int   r2 = __shfl(r, j + 2, 32), r3 = __shfl(r, j + 3, 32);
          const float w0 = __shfl(w, j, 32),     w1 = __shfl(w, j + 1, 32);
          const float w2 = __shfl(w, j + 2, 32), w3 = __shfl(w, j + 3, 32);
          const ushort4 h0 = *reinterpret_cast<const ushort4*>(&H[(size_t)r0 * HID + l * 4]);
          const ushort4 h1 = *reinterpret_cast<const ushort4*>(&H[(size_t)r1 * HID + l * 4]);
          const ushort4 h2 = *reinterpret_cast<const ushort4*>(&H[(size_t)r2 * HID + l * 4]);
          const ushort4 h3 = *reinterpret_cast<const ushort4*>(&H[(size_t)r3 * HID + l * 4]);
          a.x = fmaf(w0, bf2f(h0.x), a.x); a.y = fmaf(w0, bf2f(h0.y), a.y);
          a.z = fmaf(w0, bf2f(h0.z), a.z); a.w = fmaf(w0, bf2f(h0.w), a.w);
          a.x = fmaf(w1, bf2f(h1.x), a.x); a.y = fmaf(w1, bf2f(h1.y), a.y);
          a.z = fmaf(w1, bf2f(h1.z), a.z); a.w = fmaf(w1, bf2f(h1.w), a.w);
          a.x = fmaf(w2, bf2f(h2.x), a.x); a.y = fmaf(w2, bf2f(h2.y), a.y);
          a.z = fmaf(w2, bf2f(h2.z), a.z); a.w = fmaf(w2, bf2f(h2.w), a.w);
          a.x = fmaf(w3, bf2f(h3.x), a.x); a.y = fmaf(w3, bf2f(h3.y), a.y);
          a.z = fmaf(w3, bf2f(h3.z), a.z); a.w = fmaf(w3, bf2f(h3.w), a.w);
        }
        for (; j < np; ++j) {
          const int   rj = __shfl(r, j, 32);
          const float wj = __shfl(w, j, 32);
          const ushort4 hv = *reinterpret_cast<const ushort4*>(&H[(size_t)rj * HID + l * 4]);
          a.x = fmaf(wj, bf2f(hv.x), a.x); a.y = fmaf(wj, bf2f(hv.y), a.y);
          a.z = fmaf(wj, bf2f(hv.z), a.z); a.w = fmaf(wj, bf2f(hv.w), a.w);
        }
      }
      const float4 rv = *reinterpret_cast<const float4*>(&root[(size_t)node * HID + l * 4]);
      const float4 bv = *reinterpret_cast<const float4*>(&bias[l * 4]);
      o[0] = fmaxf(a.x + rv.x + bv.x, 0.f);
      o[1] = fmaxf(a.y + rv.y + bv.y, 0.f);
      o[2] = fmaxf(a.z + rv.z + bv.z, 0.f);
      o[3] = fmaxf(a.w + rv.w + bv.w, 0.f);
    }
    if (l == 0) gid[g] = valid ? batch[node] : -1;
    *reinterpret_cast<float4*>(&nx[g][l * 4]) = make_float4(o[0], o[1], o[2], o[3]);
    __syncthreads();
    if (f < HID) {
      for (int i = 0; i < 8; ++i) {
        const int gi = gid[i];
        if (gi < 0) continue;
        if (gi != cur) {
          if (cur >= 0) {
            atomicAdd(&gsum[cur * HID + f], acc);
            if (f == 0) atomicAdd(&gcnt[cur], crun);
          }
          acc = 0.f; crun = 0.f; cur = gi;
        }
        acc += nx[i][f]; crun += 1.f;
      }
    }
    __syncthreads();                     // nx reused next batch
  }
  if (f < HID && cur >= 0) {
    atomicAdd(&gsum[cur * HID + f], acc);
    if (f == 0) atomicAdd(&gcnt[cur], crun);
  }
}

// ---------------- graph MLP ----------------
__global__ __launch_bounds__(256)
void mlp_kernel(const float* __restrict__ gsum, const float* __restrict__ gcnt,
                const float* __restrict__ w1, const float* __restrict__ b1,
                const float* __restrict__ w2, const float* __restrict__ b2,
                float* __restrict__ out) {
  const int g = blockIdx.x;
  const int t = threadIdx.x;
  __shared__ float gx[HID];
  __shared__ float red[8];
  const float cnt = fmaxf(gcnt[g], 1.f);
  if (t < HID) gx[t] = gsum[g * HID + t] / cnt;
  __syncthreads();
  float a = b1[t];
  for (int k = 0; k < HID; ++k) a = fmaf(gx[k], w1[k * 256 + t], a);
  const float h = fmaxf(a, 0.f);
  float p0 = h * w2[t * 2 + 0];
  float p1 = h * w2[t * 2 + 1];
  for (int o = 32; o > 0; o >>= 1) { p0 += __shfl_down(p0, o, 64); p1 += __shfl_down(p1, o, 64); }
  const int lane = t & 63, wv = t >> 6;
  if (lane == 0) { red[wv * 2] = p0; red[wv * 2 + 1] = p1; }
  __syncthreads();
  if (t == 0) out[g * 2 + 0] = red[0] + red[2] + red[4] + red[6] + b2[0];
  if (t == 1) out[g * 2 + 1] = red[1] + red[3] + red[5] + red[7] + b2[1];
}

extern "C" void kernel_launch(void* const* d_in, const int* in_sizes, int n_in,
                              void* d_out, int out_size, void* d_ws, size_t ws_size,
                              hipStream_t stream) {
  const float* x       = (const float*)d_in[0];
  const int*   ei      = (const int*)d_in[1];
  const float* ea      = (const float*)d_in[2];
  const int*   batch   = (const int*)d_in[3];
  const float* w_init0 = (const float*)d_in[4];
  const float* w_root0 = (const float*)d_in[5];
  const float* b0      = (const float*)d_in[6];
  const float* w_init1 = (const float*)d_in[7];
  const float* w_root1 = (const float*)d_in[8];
  const float* b1      = (const float*)d_in[9];
  const float* mw1     = (const float*)d_in[10];
  const float* mb1     = (const float*)d_in[11];
  const float* mw2     = (const float*)d_in[12];
  const float* mb2     = (const float*)d_in[13];
  float* out = (float*)d_out;

  const int E = in_sizes[2];
  const int N = in_sizes[3];
  const int* row = ei;
  const int* col = ei + E;
  const int nb = (N + 255) / 256;

  char* ws = (char*)d_ws;
  size_t off = 0;
  auto alloc = [&](size_t bytes) -> void* {
    size_t cur = off;
    off = (cur + bytes + 255) & ~(size_t)255;
    return (void*)(ws + cur);
  };
  unsigned long long* packed = (unsigned long long*)alloc((size_t)N * 8);
  float* dinv   = (float*)alloc((size_t)N * 4);
  int*   cnt    = (int*)alloc((size_t)N * 4);
  int*   psum   = (int*)alloc((size_t)nb * 4);
  int*   rowptr = (int*)alloc((size_t)(N + 1) * 4);
  int2*  cpay   = (int2*)alloc((size_t)E * 8);
  unsigned short* B1  = (unsigned short*)alloc((size_t)N * HID * 2);  // H (bf16 gather operand)
  unsigned short* B2h = (unsigned short*)alloc((size_t)N * HID * 2);  // h hi
  unsigned short* B2l = (unsigned short*)alloc((size_t)N * HID * 2);  // h lo
  float* B3     = (float*)alloc((size_t)N * HID * 4);  // conv0 root -> conv1 root
  unsigned short* w0h = (unsigned short*)alloc((size_t)256 * F_IN * 2);
  unsigned short* w0l = (unsigned short*)alloc((size_t)256 * F_IN * 2);
  unsigned short* w1h = (unsigned short*)alloc((size_t)256 * HID * 2);
  unsigned short* w1l = (unsigned short*)alloc((size_t)256 * HID * 2);
  float* gsum   = (float*)alloc((size_t)NGRAPH * HID * 4);
  float* gcnt   = (float*)alloc((size_t)NGRAPH * 4);
  (void)ws_size; (void)n_in; (void)out_size;

  // ---- gcn_norm + CSR build + weight prep ----
  hipMemsetAsync(packed, 0, (size_t)N * 8, stream);
  deg_count_kernel<<<(E + 255) / 256, 256, 0, stream>>>(col, ea, packed, E);
  dinv_cnt_kernel<<<(N + 255) / 256, 256, 0, stream>>>(packed, dinv, cnt, N);
  scan1_kernel<<<nb, 256, 0, stream>>>(cnt, psum, N);
  scan2_kernel<<<1, 512, 0, stream>>>(psum, nb);
  scan3_kernel<<<nb, 256, 0, stream>>>(cnt, psum, rowptr, N, E);
  fill_csr_kernel<<<(E + 255) / 256, 256, 0, stream>>>(row, col, ea, dinv, rowptr, cnt,
                                                       cpay, E);
  prep_w_kernel<<<(256 * F_IN + 255) / 256, 256, 0, stream>>>(w_init0, w_root0, w0h, w0l, F_IN);
  prep_w_kernel<<<(256 * HID + 255) / 256, 256, 0, stream>>>(w_init1, w_root1, w1h, w1l, HID);

  const int gb = (N + 63) / 64;

  // ---- conv0: B1 = bf16(x@wi0), B3 = x@wr0; gather -> (B2h,B2l) = split(relu(...)) ----
  gemm_f32A<F_IN><<<gb, 256, 0, stream>>>(x, w0h, w0l, B1, B3, N);
  gather1_kernel<<<(N + 7) / 8, 256, 0, stream>>>(rowptr, cpay, B1, B3, b0, B2h, B2l, N);

  // ---- conv1: B1 = bf16(h@wi1), B3 = h@wr1; fused gather+pool (no node_x writeback) ----
  gemm_bf16A<HID><<<gb, 256, 0, stream>>>(B2h, B2l, w1h, w1l, B1, B3, N);
  hipMemsetAsync(gsum, 0, (size_t)NGRAPH * HID * 4, stream);
  hipMemsetAsync(gcnt, 0, (size_t)NGRAPH * 4, stream);
  gather_pool_kernel<<<(N + 15) / 16, 256, 0, stream>>>(rowptr, cpay, B1, B3, b1, batch,
                                                        gsum, gcnt, N);

  // ---- MLP ----
  mlp_kernel<<<NGRAPH, 256, 0, stream>>>(gsum, gcnt, mw1, mb1, mw2, mb2, out);
}